// Round 1
// baseline (651.595 us; speedup 1.0000x reference)
//
#include <hip/hip_runtime.h>

// EngramANNInjection on gfx950.
// Pipeline: qproj -> tabprep -> flash-attn (bf16 MFMA, split-T) -> combine+LN
//           -> kvproj -> gate -> causal depthwise conv + silu.
// ws layout (needs ~70.25 MB):
//   [0,2MB)    qn bf16 [4096][256]
//   [2,6MB)    retr f32 [4096][256]
//   [6MB,...)  region A:
//     phase1: tn bf16 16MB | tblT bf16 16MB | Opart f32 32MB | mpart 128KB | lpart 128KB
//     phase2 (reuses A): key bf16 16MB | value bf16 16MB | gated bf16 16MB

#define NTOK 4096
#define CDIM 2048
#define EDIM 256
#define TROWS 32768
#define SPLIT 8
#define ROWS_PER_SPLIT (TROWS / SPLIT)
#define BN 32
#define OUT0 (NTOK * CDIM)

typedef __attribute__((ext_vector_type(8))) short bf16x8;
typedef __attribute__((ext_vector_type(4))) float f32x4;

__device__ inline float bf2f(unsigned short u) {
  return __uint_as_float(((unsigned int)u) << 16);
}
__device__ inline unsigned short f2bf(float f) {
  unsigned int x = __float_as_uint(f);
  x += 0x7fffu + ((x >> 16) & 1u);  // round-to-nearest-even
  return (unsigned short)(x >> 16);
}

// ---------------- q = hidden @ Wq, l2norm, store bf16 ----------------
__global__ __launch_bounds__(256) void qproj_kernel(
    const float* __restrict__ hidden, const float* __restrict__ Wq,
    unsigned short* __restrict__ qn) {
  __shared__ float lh[16][256];
  __shared__ float wsum[4][16];
  __shared__ float scl[16];
  const int tid = threadIdx.x;
  const int wave = tid >> 6, lane = tid & 63;
  const int t0 = blockIdx.x * 16;
  float acc[16];
#pragma unroll
  for (int r = 0; r < 16; ++r) acc[r] = 0.f;
  for (int kc = 0; kc < 8; ++kc) {
    __syncthreads();
#pragma unroll
    for (int i = 0; i < 16; ++i)
      lh[i][tid] = hidden[(size_t)(t0 + i) * CDIM + kc * 256 + tid];
    __syncthreads();
    for (int k = 0; k < 256; k += 4) {
      float w0 = Wq[(size_t)(kc * 256 + k + 0) * EDIM + tid];
      float w1 = Wq[(size_t)(kc * 256 + k + 1) * EDIM + tid];
      float w2 = Wq[(size_t)(kc * 256 + k + 2) * EDIM + tid];
      float w3 = Wq[(size_t)(kc * 256 + k + 3) * EDIM + tid];
#pragma unroll
      for (int r = 0; r < 16; ++r) {
        float4 hv = *reinterpret_cast<const float4*>(&lh[r][k]);
        float a = acc[r];
        a = fmaf(hv.x, w0, a); a = fmaf(hv.y, w1, a);
        a = fmaf(hv.z, w2, a); a = fmaf(hv.w, w3, a);
        acc[r] = a;
      }
    }
  }
#pragma unroll
  for (int r = 0; r < 16; ++r) {
    float v = acc[r] * acc[r];
#pragma unroll
    for (int m = 1; m <= 32; m <<= 1) v += __shfl_xor(v, m);
    if (lane == 0) wsum[wave][r] = v;
  }
  __syncthreads();
  if (tid < 16) {
    float ss = wsum[0][tid] + wsum[1][tid] + wsum[2][tid] + wsum[3][tid];
    scl[tid] = 1.f / fmaxf(sqrtf(ss), 1e-8f);
  }
  __syncthreads();
#pragma unroll
  for (int r = 0; r < 16; ++r)
    qn[(size_t)(t0 + r) * EDIM + tid] = f2bf(acc[r] * scl[r]);
}

// ---------------- table norms; tn bf16 (normalized, row-major); tblT bf16 (raw, [E][T]) ----------------
__global__ __launch_bounds__(256) void tabprep_kernel(
    const float* __restrict__ table, unsigned short* __restrict__ tn,
    unsigned short* __restrict__ tblT) {
  __shared__ float lt[32][256];
  __shared__ float inv[32];
  const int tid = threadIdx.x;
  const int r0 = blockIdx.x * 32;
#pragma unroll
  for (int i = 0; i < 32; ++i)
    lt[i][tid] = table[(size_t)(r0 + i) * EDIM + tid];
  __syncthreads();
  {
    const int row = tid >> 3, sub = tid & 7;
    float ss = 0.f;
#pragma unroll
    for (int j = 0; j < 32; ++j) { float v = lt[row][sub + 8 * j]; ss = fmaf(v, v, ss); }
    ss += __shfl_xor(ss, 1); ss += __shfl_xor(ss, 2); ss += __shfl_xor(ss, 4);
    if (sub == 0) inv[row] = 1.f / fmaxf(sqrtf(ss), 1e-8f);
  }
  __syncthreads();
#pragma unroll
  for (int i = 0; i < 32; ++i)
    tn[(size_t)(r0 + i) * EDIM + tid] = f2bf(lt[i][tid] * inv[i]);
#pragma unroll
  for (int rb = 0; rb < 4; ++rb) {
    bf16x8 v;
#pragma unroll
    for (int j = 0; j < 8; ++j) v[j] = (short)f2bf(lt[rb * 8 + j][tid]);
    *reinterpret_cast<bf16x8*>(tblT + (size_t)tid * TROWS + r0 + rb * 8) = v;
  }
}

// ---------------- flash attention over table, bf16 MFMA, 8-way T split ----------------
__global__ __launch_bounds__(256) void attn_kernel(
    const unsigned short* __restrict__ qn, const unsigned short* __restrict__ tn,
    const unsigned short* __restrict__ tblT, float* __restrict__ Opart,
    float* __restrict__ mpart, float* __restrict__ lpart) {
  __shared__ alignas(16) unsigned short ldsK[32][264];    // +8 pad -> 2-way banks on b128
  __shared__ alignas(16) unsigned short ldsV[256][40];    // V transposed slice [e][n]
  __shared__ alignas(16) unsigned short pbuf[4][16 * 40]; // wave-private P round-trip
  const int tid = threadIdx.x;
  const int wave = tid >> 6, lane = tid & 63;
  const int laneLo = lane & 15, laneHi = lane >> 4;
  const int split = blockIdx.y;
  const int t0 = blockIdx.x * 64 + wave * 16;
  // Q fragments (B-operand of S^T = Tn * Qn^T): lane holds Qn[t0+laneLo][k]
  bf16x8 qf[8];
#pragma unroll
  for (int ks = 0; ks < 8; ++ks)
    qf[ks] = *reinterpret_cast<const bf16x8*>(
        qn + (size_t)(t0 + laneLo) * EDIM + ks * 32 + laneHi * 8);
  f32x4 o[16];
#pragma unroll
  for (int f = 0; f < 16; ++f) o[f] = (f32x4){0.f, 0.f, 0.f, 0.f};
  float m_run = -1e30f, l_run = 0.f;
  const int nbase = split * ROWS_PER_SPLIT;
  for (int it = 0; it < ROWS_PER_SPLIT / BN; ++it) {
    const int n0 = nbase + it * BN;
    __syncthreads();
#pragma unroll
    for (int u0 = 0; u0 < 4; ++u0) {
      int u = u0 * 256 + tid;
      int row = u >> 5, c8 = u & 31;
      *reinterpret_cast<bf16x8*>(&ldsK[row][c8 * 8]) =
          *reinterpret_cast<const bf16x8*>(tn + (size_t)(n0 + row) * EDIM + c8 * 8);
      int e = u >> 2, n8 = u & 3;
      *reinterpret_cast<bf16x8*>(&ldsV[e][n8 * 8]) =
          *reinterpret_cast<const bf16x8*>(tblT + (size_t)e * TROWS + n0 + n8 * 8);
    }
    __syncthreads();
    // S^T: Z[n][tok], n-subtiles of 16
    f32x4 z0 = {0.f, 0.f, 0.f, 0.f}, z1 = {0.f, 0.f, 0.f, 0.f};
#pragma unroll
    for (int ks = 0; ks < 8; ++ks) {
      bf16x8 a0 = *reinterpret_cast<const bf16x8*>(&ldsK[laneLo][ks * 32 + laneHi * 8]);
      z0 = __builtin_amdgcn_mfma_f32_16x16x32_bf16(a0, qf[ks], z0, 0, 0, 0);
    }
#pragma unroll
    for (int ks = 0; ks < 8; ++ks) {
      bf16x8 a1 = *reinterpret_cast<const bf16x8*>(&ldsK[16 + laneLo][ks * 32 + laneHi * 8]);
      z1 = __builtin_amdgcn_mfma_f32_16x16x32_bf16(a1, qf[ks], z1, 0, 0, 0);
    }
    // online softmax; token = laneLo, rows n = laneHi*4+reg (+16 for z1)
    float s[8];
#pragma unroll
    for (int r = 0; r < 4; ++r) { s[r] = z0[r] * 16.f; s[4 + r] = z1[r] * 16.f; }
    float cmax = s[0];
#pragma unroll
    for (int i = 1; i < 8; ++i) cmax = fmaxf(cmax, s[i]);
    cmax = fmaxf(cmax, __shfl_xor(cmax, 16));
    cmax = fmaxf(cmax, __shfl_xor(cmax, 32));
    const float newm = fmaxf(m_run, cmax);
    const float sc_old = __expf(m_run - newm);
    float p[8], psum = 0.f;
#pragma unroll
    for (int i = 0; i < 8; ++i) { p[i] = __expf(s[i] - newm); psum += p[i]; }
    psum += __shfl_xor(psum, 16);
    psum += __shfl_xor(psum, 32);
    l_run = l_run * sc_old + psum;
    m_run = newm;
    // write P bf16 into wave-private pbuf[token][n]
    unsigned short* pb = &pbuf[wave][0];
    {
      unsigned int a = (unsigned int)f2bf(p[0]) | ((unsigned int)f2bf(p[1]) << 16);
      unsigned int b = (unsigned int)f2bf(p[2]) | ((unsigned int)f2bf(p[3]) << 16);
      unsigned int c = (unsigned int)f2bf(p[4]) | ((unsigned int)f2bf(p[5]) << 16);
      unsigned int d = (unsigned int)f2bf(p[6]) | ((unsigned int)f2bf(p[7]) << 16);
      int off = laneLo * 40 + laneHi * 4;
      *reinterpret_cast<unsigned int*>(pb + off) = a;
      *reinterpret_cast<unsigned int*>(pb + off + 2) = b;
      *reinterpret_cast<unsigned int*>(pb + off + 16) = c;
      *reinterpret_cast<unsigned int*>(pb + off + 18) = d;
    }
    // rescale O accumulators; O rows are tokens laneHi*4+r
    float scr0 = __shfl(sc_old, laneHi * 4 + 0);
    float scr1 = __shfl(sc_old, laneHi * 4 + 1);
    float scr2 = __shfl(sc_old, laneHi * 4 + 2);
    float scr3 = __shfl(sc_old, laneHi * 4 + 3);
#pragma unroll
    for (int f = 0; f < 16; ++f) {
      o[f][0] *= scr0; o[f][1] *= scr1; o[f][2] *= scr2; o[f][3] *= scr3;
    }
    asm volatile("s_waitcnt lgkmcnt(0)" ::: "memory");
    __builtin_amdgcn_sched_barrier(0);
    // PV: A = P[token][n] (b128 from pbuf), B = V[n][e] from ldsV[e][n]
    bf16x8 pa = *reinterpret_cast<const bf16x8*>(pb + laneLo * 40 + laneHi * 8);
#pragma unroll
    for (int f = 0; f < 16; ++f) {
      bf16x8 vb = *reinterpret_cast<const bf16x8*>(&ldsV[f * 16 + laneLo][laneHi * 8]);
      o[f] = __builtin_amdgcn_mfma_f32_16x16x32_bf16(pa, vb, o[f], 0, 0, 0);
    }
  }
  // store partial O (unnormalized), m, l
#pragma unroll
  for (int f = 0; f < 16; ++f)
#pragma unroll
    for (int r = 0; r < 4; ++r)
      Opart[((size_t)split * NTOK + t0 + laneHi * 4 + r) * EDIM + f * 16 + laneLo] = o[f][r];
  if (lane < 16) {
    mpart[split * NTOK + t0 + lane] = m_run;
    lpart[split * NTOK + t0 + lane] = l_run;
  }
}

// ---------------- combine splits + layernorm ----------------
__global__ __launch_bounds__(256) void combine_ln_kernel(
    const float* __restrict__ Opart, const float* __restrict__ mpart,
    const float* __restrict__ lpart, const float* __restrict__ gamma,
    const float* __restrict__ beta, float* __restrict__ retr) {
  __shared__ float red[4][2];
  const int t = blockIdx.x, e = threadIdx.x;
  const int wave = e >> 6, lane = e & 63;
  float mv[SPLIT];
  float m = -1e30f;
#pragma unroll
  for (int i = 0; i < SPLIT; ++i) { mv[i] = mpart[i * NTOK + t]; m = fmaxf(m, mv[i]); }
  float den = 0.f, acc = 0.f;
#pragma unroll
  for (int i = 0; i < SPLIT; ++i) {
    float w = __expf(mv[i] - m);
    den = fmaf(w, lpart[i * NTOK + t], den);
    acc = fmaf(w, Opart[((size_t)i * NTOK + t) * EDIM + e], acc);
  }
  const float r = acc / den;
  float s1 = r, s2 = r * r;
#pragma unroll
  for (int msk = 1; msk <= 32; msk <<= 1) { s1 += __shfl_xor(s1, msk); s2 += __shfl_xor(s2, msk); }
  if (lane == 0) { red[wave][0] = s1; red[wave][1] = s2; }
  __syncthreads();
  s1 = red[0][0] + red[1][0] + red[2][0] + red[3][0];
  s2 = red[0][1] + red[1][1] + red[2][1] + red[3][1];
  const float mu = s1 * (1.f / 256.f);
  const float var = s2 * (1.f / 256.f) - mu * mu;
  const float rs = rsqrtf(var + 1e-6f);
  retr[(size_t)t * EDIM + e] = (r - mu) * rs * gamma[e] + beta[e];
}

// ---------------- key/value = retr @ Wk/Wv ----------------
__global__ __launch_bounds__(256) void kvproj_kernel(
    const float* __restrict__ retr, const float* __restrict__ Wk,
    const float* __restrict__ Wv, unsigned short* __restrict__ keyb,
    unsigned short* __restrict__ valb) {
  __shared__ float lr[16][256];
  const int tid = threadIdx.x;
  const int t0 = blockIdx.x * 16;
  const int c = blockIdx.y * 256 + tid;
#pragma unroll
  for (int i = 0; i < 16; ++i) lr[i][tid] = retr[(size_t)(t0 + i) * EDIM + tid];
  __syncthreads();
  float ak[16], av[16];
#pragma unroll
  for (int r = 0; r < 16; ++r) { ak[r] = 0.f; av[r] = 0.f; }
  for (int e = 0; e < 256; e += 4) {
    float kw0 = Wk[(size_t)(e + 0) * CDIM + c], vw0 = Wv[(size_t)(e + 0) * CDIM + c];
    float kw1 = Wk[(size_t)(e + 1) * CDIM + c], vw1 = Wv[(size_t)(e + 1) * CDIM + c];
    float kw2 = Wk[(size_t)(e + 2) * CDIM + c], vw2 = Wv[(size_t)(e + 2) * CDIM + c];
    float kw3 = Wk[(size_t)(e + 3) * CDIM + c], vw3 = Wv[(size_t)(e + 3) * CDIM + c];
#pragma unroll
    for (int r = 0; r < 16; ++r) {
      float4 x = *reinterpret_cast<const float4*>(&lr[r][e]);
      float a = ak[r], b = av[r];
      a = fmaf(x.x, kw0, a); b = fmaf(x.x, vw0, b);
      a = fmaf(x.y, kw1, a); b = fmaf(x.y, vw1, b);
      a = fmaf(x.z, kw2, a); b = fmaf(x.z, vw2, b);
      a = fmaf(x.w, kw3, a); b = fmaf(x.w, vw3, b);
      ak[r] = a; av[r] = b;
    }
  }
#pragma unroll
  for (int r = 0; r < 16; ++r) {
    keyb[(size_t)(t0 + r) * CDIM + c] = f2bf(ak[r]);
    valb[(size_t)(t0 + r) * CDIM + c] = f2bf(av[r]);
  }
}

// ---------------- rmsnorms + gate + gated ----------------
__global__ __launch_bounds__(256) void gate_kernel(
    const float* __restrict__ hidden, const unsigned short* __restrict__ keyb,
    const unsigned short* __restrict__ valb, const float* __restrict__ gw,
    const float* __restrict__ kwn, unsigned short* __restrict__ gatedb,
    float* __restrict__ gate_out) {
  __shared__ float red[4][3];
  const int t = blockIdx.x, tid = threadIdx.x;
  const int wave = tid >> 6, lane = tid & 63;
  float vv[8];
  float ssh = 0.f, ssk = 0.f, shk = 0.f;
#pragma unroll
  for (int i = 0; i < 8; ++i) {
    int cc = tid + i * 256;
    float h = hidden[(size_t)t * CDIM + cc];
    float k = bf2f(keyb[(size_t)t * CDIM + cc]);
    vv[i] = bf2f(valb[(size_t)t * CDIM + cc]);
    ssh = fmaf(h, h, ssh);
    ssk = fmaf(k, k, ssk);
    shk = fmaf(h * gw[cc], k * kwn[cc], shk);
  }
#pragma unroll
  for (int m = 1; m <= 32; m <<= 1) {
    ssh += __shfl_xor(ssh, m); ssk += __shfl_xor(ssk, m); shk += __shfl_xor(shk, m);
  }
  if (lane == 0) { red[wave][0] = ssh; red[wave][1] = ssk; red[wave][2] = shk; }
  __syncthreads();
  ssh = red[0][0] + red[1][0] + red[2][0] + red[3][0];
  ssk = red[0][1] + red[1][1] + red[2][1] + red[3][1];
  shk = red[0][2] + red[1][2] + red[2][2] + red[3][2];
  const float rsh = rsqrtf(ssh * (1.f / 2048.f) + 1e-6f);
  const float rsk = rsqrtf(ssk * (1.f / 2048.f) + 1e-6f);
  const float dot = rsh * rsk * shk;
  const float rg = 1.f / (1.f + __expf(-dot * 0.02209708691207961f));  // 1/sqrt(2048)
  const float gate = fmaxf(rg, 0.5f);
  if (tid == 0) gate_out[t] = gate;
#pragma unroll
  for (int i = 0; i < 8; ++i) {
    int cc = tid + i * 256;
    gatedb[(size_t)t * CDIM + cc] = f2bf(gate * vv[i]);
  }
}

// ---------------- causal depthwise conv (K=3) + silu ----------------
__global__ __launch_bounds__(256) void conv_kernel(
    const unsigned short* __restrict__ gatedb, const float* __restrict__ convw,
    float* __restrict__ out0) {
  const int t = blockIdx.x, tid = threadIdx.x;
  const int l = t & 1023;
  const int c0 = tid * 8;
  bf16x8 gz;
#pragma unroll
  for (int j = 0; j < 8; ++j) gz[j] = 0;
  bf16x8 g2 = *reinterpret_cast<const bf16x8*>(gatedb + (size_t)t * CDIM + c0);
  bf16x8 g1 = (l >= 1) ? *reinterpret_cast<const bf16x8*>(gatedb + (size_t)(t - 1) * CDIM + c0) : gz;
  bf16x8 g0 = (l >= 2) ? *reinterpret_cast<const bf16x8*>(gatedb + (size_t)(t - 2) * CDIM + c0) : gz;
  float res[8];
#pragma unroll
  for (int j = 0; j < 8; ++j) {
    int c = c0 + j;
    float x = convw[c * 3 + 0] * bf2f((unsigned short)g0[j])
            + convw[c * 3 + 1] * bf2f((unsigned short)g1[j])
            + convw[c * 3 + 2] * bf2f((unsigned short)g2[j]);
    res[j] = x / (1.f + __expf(-x));
  }
  *reinterpret_cast<float4*>(out0 + (size_t)t * CDIM + c0) =
      make_float4(res[0], res[1], res[2], res[3]);
  *reinterpret_cast<float4*>(out0 + (size_t)t * CDIM + c0 + 4) =
      make_float4(res[4], res[5], res[6], res[7]);
}

extern "C" void kernel_launch(void* const* d_in, const int* in_sizes, int n_in,
                              void* d_out, int out_size, void* d_ws, size_t ws_size,
                              hipStream_t stream) {
  const float* hidden = (const float*)d_in[0];
  const float* table  = (const float*)d_in[1];
  const float* Wq     = (const float*)d_in[2];
  const float* ln_g   = (const float*)d_in[3];
  const float* ln_b   = (const float*)d_in[4];
  const float* Wk     = (const float*)d_in[5];
  const float* Wv     = (const float*)d_in[6];
  const float* gnw    = (const float*)d_in[7];
  const float* knw    = (const float*)d_in[8];
  const float* convw  = (const float*)d_in[9];
  float* out = (float*)d_out;

  char* w = (char*)d_ws;
  unsigned short* qn   = (unsigned short*)(w);
  float* retr          = (float*)(w + (2u << 20));
  char* rA             = w + (6u << 20);
  unsigned short* tn   = (unsigned short*)(rA);
  unsigned short* tblT = (unsigned short*)(rA + (16u << 20));
  float* Opart         = (float*)(rA + (32u << 20));
  float* mpart         = (float*)(rA + (64u << 20));
  float* lpart         = (float*)(rA + (64u << 20) + (1u << 17));
  // phase-2 aliases (tn/tblT/Opart dead by then)
  unsigned short* keyb   = (unsigned short*)(rA);
  unsigned short* valb   = (unsigned short*)(rA + (16u << 20));
  unsigned short* gatedb = (unsigned short*)(rA + (32u << 20));

  qproj_kernel<<<NTOK / 16, 256, 0, stream>>>(hidden, Wq, qn);
  tabprep_kernel<<<TROWS / 32, 256, 0, stream>>>(table, tn, tblT);
  attn_kernel<<<dim3(NTOK / 64, SPLIT), 256, 0, stream>>>(qn, tn, tblT, Opart, mpart, lpart);
  combine_ln_kernel<<<NTOK, 256, 0, stream>>>(Opart, mpart, lpart, ln_g, ln_b, retr);
  kvproj_kernel<<<dim3(NTOK / 16, CDIM / 256), 256, 0, stream>>>(retr, Wk, Wv, keyb, valb);
  gate_kernel<<<NTOK, 256, 0, stream>>>(hidden, keyb, valb, gnw, knw, gatedb, out + OUT0);
  conv_kernel<<<NTOK, 256, 0, stream>>>(gatedb, convw, out);
}

// Round 2
// 245.711 us; speedup vs baseline: 2.6519x; 2.6519x over previous
//
#include <hip/hip_runtime.h>
#include <stdint.h>

// EngramANNInjection v2: fixed-max flash attention (logit max == 16 exactly since
// sims are cosine * 16), 32 tokens/wave (2x fragment reuse), global_load_lds
// double-buffered staging from pre-blocked table layouts, bf16 MFMA GEMMs for
// q/k/v projections.

#define NTOK 4096
#define CDIM 2048
#define EDIM 256
#define TROWS 32768
#define SPLIT 16
#define BN 32
#define OUT0 (NTOK * CDIM)

typedef __attribute__((ext_vector_type(8))) short bf16x8;
typedef __attribute__((ext_vector_type(4))) short bf16x4;
typedef __attribute__((ext_vector_type(4))) float f32x4;

__device__ inline float bf2f(unsigned short u) { return __uint_as_float((unsigned)u << 16); }
__device__ inline unsigned short f2bf(float f) {
  unsigned x = __float_as_uint(f);
  x += 0x7fffu + ((x >> 16) & 1u);  // RNE
  return (unsigned short)(x >> 16);
}
__device__ inline unsigned cvt_pk_bf16(float lo, float hi) {
  unsigned r;
  asm("v_cvt_pk_bf16_f32 %0, %1, %2" : "=v"(r) : "v"(lo), "v"(hi));
  return r;
}
__device__ inline void gll16(const void* g, void* l) {
  __builtin_amdgcn_global_load_lds((const __attribute__((address_space(1))) void*)g,
                                   (__attribute__((address_space(3))) void*)l, 16, 0, 0);
}

// ---------------- fp32 -> bf16 cast (hidden) ----------------
__global__ __launch_bounds__(256) void cast_bf16_kernel(
    const float* __restrict__ in, unsigned short* __restrict__ out) {
  const int idx = blockIdx.x * 256 + threadIdx.x;
  float4 v0 = *reinterpret_cast<const float4*>(&in[(size_t)idx * 8]);
  float4 v1 = *reinterpret_cast<const float4*>(&in[(size_t)idx * 8 + 4]);
  bf16x8 o;
  o[0] = (short)f2bf(v0.x); o[1] = (short)f2bf(v0.y);
  o[2] = (short)f2bf(v0.z); o[3] = (short)f2bf(v0.w);
  o[4] = (short)f2bf(v1.x); o[5] = (short)f2bf(v1.y);
  o[6] = (short)f2bf(v1.z); o[7] = (short)f2bf(v1.w);
  *reinterpret_cast<bf16x8*>(&out[(size_t)idx * 8]) = o;
}

// ---------------- transpose + cast: in f32 [R][C] -> out bf16 [C][R] ----------------
__global__ __launch_bounds__(256) void transpose_cast_kernel(
    const float* __restrict__ in, unsigned short* __restrict__ out, int R, int C) {
  __shared__ float lt[32][33];
  const int tid = threadIdx.x;
  const int r0 = blockIdx.x * 32, c0 = blockIdx.y * 32;
  {
    int r = tid >> 3, c4 = (tid & 7) * 4;
    float4 v = *reinterpret_cast<const float4*>(&in[(size_t)(r0 + r) * C + c0 + c4]);
    lt[r][c4] = v.x; lt[r][c4 + 1] = v.y; lt[r][c4 + 2] = v.z; lt[r][c4 + 3] = v.w;
  }
  __syncthreads();
  {
    int c = tid >> 3, r4 = (tid & 7) * 4;
#pragma unroll
    for (int j = 0; j < 4; ++j)
      out[(size_t)(c0 + c) * R + r0 + r4 + j] = f2bf(lt[r4 + j][c]);
  }
}

// ---------------- table prep: normalized K (blocked) + raw V (blocked) ----------------
// tnb[nb][c8 32][row 32][8]  = l2norm(table[nb*32+row])[c8*8+j]   (A-frag staging order)
// tvb[nb][hi 4][e 256][8]    = table[nb*32+hi*8+j][e]             (B-frag staging order)
__global__ __launch_bounds__(256) void tabprep_kernel(
    const float* __restrict__ table, unsigned short* __restrict__ tnb,
    unsigned short* __restrict__ tvb) {
  __shared__ float lt[32][257];
  __shared__ float inv[32];
  const int tid = threadIdx.x, nb = blockIdx.x;
  const int r0 = nb * 32;
#pragma unroll
  for (int i = 0; i < 8; ++i) {
    int id = i * 256 + tid;
    int row = id >> 6, e4 = (id & 63) * 4;
    float4 v = *reinterpret_cast<const float4*>(&table[(size_t)(r0 + row) * EDIM + e4]);
    lt[row][e4] = v.x; lt[row][e4 + 1] = v.y; lt[row][e4 + 2] = v.z; lt[row][e4 + 3] = v.w;
  }
  __syncthreads();
  {
    int row = tid >> 3, sub = tid & 7;
    float ss = 0.f;
#pragma unroll
    for (int j = 0; j < 32; ++j) { float v = lt[row][sub + 8 * j]; ss = fmaf(v, v, ss); }
    ss += __shfl_xor(ss, 1); ss += __shfl_xor(ss, 2); ss += __shfl_xor(ss, 4);
    if (sub == 0) inv[row] = 1.f / fmaxf(sqrtf(ss), 1e-8f);
  }
  __syncthreads();
#pragma unroll
  for (int i = 0; i < 4; ++i) {
    int q = i * 256 + tid;
    {
      int c8 = q >> 5, row = q & 31;
      bf16x8 v;
#pragma unroll
      for (int j = 0; j < 8; ++j) v[j] = (short)f2bf(lt[row][c8 * 8 + j] * inv[row]);
      *reinterpret_cast<bf16x8*>(&tnb[(size_t)nb * 8192 + q * 8]) = v;
    }
    {
      int hi = q >> 8, e = q & 255;
      bf16x8 v;
#pragma unroll
      for (int j = 0; j < 8; ++j) v[j] = (short)f2bf(lt[hi * 8 + j][e]);
      *reinterpret_cast<bf16x8*>(&tvb[(size_t)nb * 8192 + q * 8]) = v;
    }
  }
}

// ---------------- generic bf16 GEMM: C[M][N] = A[M][K] * BT[N][K]^T ----------------
// 128x128 tile, BK=64, 4 waves (2x2, 64x64 each), global_load_lds staging with
// XOR-swizzled source (T2), double-buffered, 1 barrier/iter.
__global__ __launch_bounds__(256, 2) void gemm_bt_kernel(
    const unsigned short* __restrict__ A, const unsigned short* __restrict__ BT,
    unsigned short* __restrict__ C, int M, int N, int K) {
  __shared__ alignas(16) unsigned short sA[2][128 * 64];
  __shared__ alignas(16) unsigned short sB[2][128 * 64];
  const int tid = threadIdx.x;
  const int lane = tid & 63;
  const int wave = tid >> 6;
  const int laneLo = lane & 15, laneHi = lane >> 4;
  const int nbn = N >> 7;
  const int bm = blockIdx.x / nbn, bn = blockIdx.x % nbn;
  const int wr = wave >> 1, wc = wave & 1;
  f32x4 acc[4][4];
#pragma unroll
  for (int m = 0; m < 4; ++m)
#pragma unroll
    for (int n = 0; n < 4; ++n) acc[m][n] = (f32x4){0.f, 0.f, 0.f, 0.f};
  const int nkt = K >> 6;
  auto STAGE = [&](int b, int kt) {
#pragma unroll
    for (int i = 0; i < 4; ++i) {
      int q = i * 256 + tid;
      int row = q >> 3, cl = q & 7;
      int cs = cl ^ (row & 7);
      gll16(A + ((size_t)(bm * 128 + row) * K + kt * 64 + cs * 8), &sA[b][q * 8]);
      gll16(BT + ((size_t)(bn * 128 + row) * K + kt * 64 + cs * 8), &sB[b][q * 8]);
    }
  };
  STAGE(0, 0);
  for (int kt = 0; kt < nkt; ++kt) {
    __syncthreads();
    if (kt + 1 < nkt) STAGE((kt & 1) ^ 1, kt + 1);
    const unsigned short* pA = sA[kt & 1];
    const unsigned short* pB = sB[kt & 1];
#pragma unroll
    for (int ks = 0; ks < 2; ++ks) {
      bf16x8 af[4], bfr[4];
#pragma unroll
      for (int m = 0; m < 4; ++m) {
        int row = wr * 64 + m * 16 + laneLo;
        af[m] = *reinterpret_cast<const bf16x8*>(&pA[(row * 8 + ((ks * 4 + laneHi) ^ (row & 7))) * 8]);
      }
#pragma unroll
      for (int n = 0; n < 4; ++n) {
        int row = wc * 64 + n * 16 + laneLo;
        bfr[n] = *reinterpret_cast<const bf16x8*>(&pB[(row * 8 + ((ks * 4 + laneHi) ^ (row & 7))) * 8]);
      }
#pragma unroll
      for (int m = 0; m < 4; ++m)
#pragma unroll
        for (int n = 0; n < 4; ++n)
          acc[m][n] = __builtin_amdgcn_mfma_f32_16x16x32_bf16(af[m], bfr[n], acc[m][n], 0, 0, 0);
    }
  }
#pragma unroll
  for (int m = 0; m < 4; ++m)
#pragma unroll
    for (int n = 0; n < 4; ++n)
#pragma unroll
      for (int r = 0; r < 4; ++r)
        C[(size_t)(bm * 128 + wr * 64 + m * 16 + laneHi * 4 + r) * N +
          bn * 128 + wc * 64 + n * 16 + laneLo] = f2bf(acc[m][n][r]);
}

// ---------------- q row l2-norm: qb bf16 [4096][256] -> qn bf16 ----------------
__global__ __launch_bounds__(64) void normq_kernel(
    const unsigned short* __restrict__ qb, unsigned short* __restrict__ qn) {
  const int r = blockIdx.x, lane = threadIdx.x;
  bf16x4 v = *reinterpret_cast<const bf16x4*>(&qb[(size_t)r * EDIM + lane * 4]);
  float f0 = bf2f((unsigned short)v[0]), f1 = bf2f((unsigned short)v[1]);
  float f2 = bf2f((unsigned short)v[2]), f3 = bf2f((unsigned short)v[3]);
  float ss = f0 * f0 + f1 * f1 + f2 * f2 + f3 * f3;
#pragma unroll
  for (int m = 1; m <= 32; m <<= 1) ss += __shfl_xor(ss, m);
  const float inv = 1.f / fmaxf(sqrtf(ss), 1e-8f);
  bf16x4 o;
  o[0] = (short)f2bf(f0 * inv); o[1] = (short)f2bf(f1 * inv);
  o[2] = (short)f2bf(f2 * inv); o[3] = (short)f2bf(f3 * inv);
  *reinterpret_cast<bf16x4*>(&qn[(size_t)r * EDIM + lane * 4]) = o;
}

// ---------------- flash attention, fixed max = 16, 32 tokens/wave ----------------
__global__ __launch_bounds__(256, 2) void attn_kernel(
    const unsigned short* __restrict__ qn, const unsigned short* __restrict__ tnb,
    const unsigned short* __restrict__ tvb, unsigned short* __restrict__ Opart,
    float* __restrict__ lpart) {
  __shared__ alignas(16) unsigned short bufK[2][32 * 256];
  __shared__ alignas(16) unsigned short bufV[2][32 * 256];
  __shared__ alignas(16) unsigned short pbuf[4][2][4][16][8];
  const int tid = threadIdx.x;
  const int wave = tid >> 6, lane = tid & 63;
  const int laneLo = lane & 15, laneHi = lane >> 4;
  const int split = blockIdx.y;
  const int tokBase = blockIdx.x * 128 + wave * 32;
  bf16x8 qf[2][8];
#pragma unroll
  for (int g = 0; g < 2; ++g)
#pragma unroll
    for (int ks = 0; ks < 8; ++ks)
      qf[g][ks] = *reinterpret_cast<const bf16x8*>(
          qn + (size_t)(tokBase + g * 16 + laneLo) * EDIM + ks * 32 + laneHi * 8);
  f32x4 o[2][16];
#pragma unroll
  for (int g = 0; g < 2; ++g)
#pragma unroll
    for (int f = 0; f < 16; ++f) o[g][f] = (f32x4){0.f, 0.f, 0.f, 0.f};
  float l_run[2] = {0.f, 0.f};
  const int nt = (TROWS / SPLIT) / BN;  // 64
  const int nb0 = split * nt;
  {
    const unsigned short* sk = tnb + (size_t)nb0 * 8192;
    const unsigned short* sv = tvb + (size_t)nb0 * 8192;
#pragma unroll
    for (int i = 0; i < 4; ++i) {
      gll16(sk + (i * 256 + tid) * 8, &bufK[0][(i * 256 + tid) * 8]);
      gll16(sv + (i * 256 + tid) * 8, &bufV[0][(i * 256 + tid) * 8]);
    }
  }
  for (int it = 0; it < nt; ++it) {
    __syncthreads();  // drains prev prefetch (issued one compute-phase ago)
    const int cur = it & 1;
    if (it + 1 < nt) {
      const unsigned short* sk = tnb + (size_t)(nb0 + it + 1) * 8192;
      const unsigned short* sv = tvb + (size_t)(nb0 + it + 1) * 8192;
#pragma unroll
      for (int i = 0; i < 4; ++i) {
        gll16(sk + (i * 256 + tid) * 8, &bufK[cur ^ 1][(i * 256 + tid) * 8]);
        gll16(sv + (i * 256 + tid) * 8, &bufV[cur ^ 1][(i * 256 + tid) * 8]);
      }
    }
    // QK^T: S^T[n][tok], K-frags shared across both token groups
    f32x4 z00 = {0.f, 0.f, 0.f, 0.f}, z01 = z00, z10 = z00, z11 = z00;
#pragma unroll
    for (int ks = 0; ks < 8; ++ks) {
      const int c8 = ks * 4 + laneHi;
      bf16x8 a0 = *reinterpret_cast<const bf16x8*>(&bufK[cur][(c8 * 32 + laneLo) * 8]);
      bf16x8 a1 = *reinterpret_cast<const bf16x8*>(&bufK[cur][(c8 * 32 + 16 + laneLo) * 8]);
      z00 = __builtin_amdgcn_mfma_f32_16x16x32_bf16(a0, qf[0][ks], z00, 0, 0, 0);
      z01 = __builtin_amdgcn_mfma_f32_16x16x32_bf16(a1, qf[0][ks], z01, 0, 0, 0);
      z10 = __builtin_amdgcn_mfma_f32_16x16x32_bf16(a0, qf[1][ks], z10, 0, 0, 0);
      z11 = __builtin_amdgcn_mfma_f32_16x16x32_bf16(a1, qf[1][ks], z11, 0, 0, 0);
    }
    // softmax with FIXED max 16 (logits <= 16 by construction): p = exp(16*z - 16)
#pragma unroll
    for (int g = 0; g < 2; ++g) {
      const f32x4 za = g ? z10 : z00;
      const f32x4 zb = g ? z11 : z01;
      float p[8];
#pragma unroll
      for (int r = 0; r < 4; ++r) {
        p[r] = __expf(fmaf(16.f, za[r], -16.f));
        p[4 + r] = __expf(fmaf(16.f, zb[r], -16.f));
      }
      l_run[g] += ((p[0] + p[1]) + (p[2] + p[3])) + ((p[4] + p[5]) + (p[6] + p[7]));
      const int hi2 = laneHi >> 1, j0 = (laneHi & 1) * 4;
      *reinterpret_cast<uint2*>(&pbuf[wave][g][hi2][laneLo][j0]) =
          make_uint2(cvt_pk_bf16(p[0], p[1]), cvt_pk_bf16(p[2], p[3]));
      *reinterpret_cast<uint2*>(&pbuf[wave][g][2 + hi2][laneLo][j0]) =
          make_uint2(cvt_pk_bf16(p[4], p[5]), cvt_pk_bf16(p[6], p[7]));
    }
    asm volatile("s_waitcnt lgkmcnt(0)" ::: "memory");
    __builtin_amdgcn_sched_barrier(0);
    bf16x8 pa0 = *reinterpret_cast<const bf16x8*>(&pbuf[wave][0][laneHi][laneLo][0]);
    bf16x8 pa1 = *reinterpret_cast<const bf16x8*>(&pbuf[wave][1][laneHi][laneLo][0]);
    // PV: V-frags shared across both token groups
#pragma unroll
    for (int f = 0; f < 16; ++f) {
      bf16x8 vb = *reinterpret_cast<const bf16x8*>(
          &bufV[cur][(laneHi * 256 + f * 16 + laneLo) * 8]);
      o[0][f] = __builtin_amdgcn_mfma_f32_16x16x32_bf16(pa0, vb, o[0][f], 0, 0, 0);
      o[1][f] = __builtin_amdgcn_mfma_f32_16x16x32_bf16(pa1, vb, o[1][f], 0, 0, 0);
    }
  }
#pragma unroll
  for (int g = 0; g < 2; ++g) {
    float l = l_run[g];
    l += __shfl_xor(l, 16);
    l += __shfl_xor(l, 32);
    if (lane < 16) lpart[(size_t)split * NTOK + tokBase + g * 16 + laneLo] = l;
#pragma unroll
    for (int f = 0; f < 16; ++f)
#pragma unroll
      for (int r = 0; r < 4; ++r)
        Opart[((size_t)split * NTOK + tokBase + g * 16 + laneHi * 4 + r) * EDIM +
              f * 16 + laneLo] = f2bf(o[g][f][r]);
  }
}

// ---------------- combine splits (plain sum, shared max) + layernorm ----------------
__global__ __launch_bounds__(256) void combine_ln_kernel(
    const unsigned short* __restrict__ Opart, const float* __restrict__ lpart,
    const float* __restrict__ gamma, const float* __restrict__ beta,
    unsigned short* __restrict__ retr) {
  __shared__ float red[4][2];
  const int t = blockIdx.x, e = threadIdx.x;
  const int wave = e >> 6, lane = e & 63;
  float acc = 0.f, l = 0.f;
#pragma unroll
  for (int s = 0; s < SPLIT; ++s) {
    acc += bf2f(Opart[((size_t)s * NTOK + t) * EDIM + e]);
    l += lpart[(size_t)s * NTOK + t];
  }
  const float r = acc / l;
  float s1 = r, s2 = r * r;
#pragma unroll
  for (int m = 1; m <= 32; m <<= 1) { s1 += __shfl_xor(s1, m); s2 += __shfl_xor(s2, m); }
  if (lane == 0) { red[wave][0] = s1; red[wave][1] = s2; }
  __syncthreads();
  s1 = red[0][0] + red[1][0] + red[2][0] + red[3][0];
  s2 = red[0][1] + red[1][1] + red[2][1] + red[3][1];
  const float mu = s1 * (1.f / 256.f);
  const float var = s2 * (1.f / 256.f) - mu * mu;
  const float rs = rsqrtf(var + 1e-6f);
  retr[(size_t)t * EDIM + e] = f2bf((r - mu) * rs * gamma[e] + beta[e]);
}

// ---------------- rmsnorms + gate + gated ----------------
__global__ __launch_bounds__(256) void gate_kernel(
    const float* __restrict__ hidden, const unsigned short* __restrict__ kv,
    const float* __restrict__ gw, const float* __restrict__ kwn,
    unsigned short* __restrict__ gatedb, float* __restrict__ gate_out) {
  __shared__ float red[4][3];
  const int t = blockIdx.x, tid = threadIdx.x;
  const int wave = tid >> 6, lane = tid & 63;
  float vv[8];
  float ssh = 0.f, ssk = 0.f, shk = 0.f;
#pragma unroll
  for (int i = 0; i < 8; ++i) {
    int cc = tid + i * 256;
    float h = hidden[(size_t)t * CDIM + cc];
    float k = bf2f(kv[(size_t)t * 4096 + cc]);
    vv[i] = bf2f(kv[(size_t)t * 4096 + 2048 + cc]);
    ssh = fmaf(h, h, ssh);
    ssk = fmaf(k, k, ssk);
    shk = fmaf(h * gw[cc], k * kwn[cc], shk);
  }
#pragma unroll
  for (int m = 1; m <= 32; m <<= 1) {
    ssh += __shfl_xor(ssh, m); ssk += __shfl_xor(ssk, m); shk += __shfl_xor(shk, m);
  }
  if (lane == 0) { red[wave][0] = ssh; red[wave][1] = ssk; red[wave][2] = shk; }
  __syncthreads();
  ssh = red[0][0] + red[1][0] + red[2][0] + red[3][0];
  ssk = red[0][1] + red[1][1] + red[2][1] + red[3][1];
  shk = red[0][2] + red[1][2] + red[2][2] + red[3][2];
  const float rsh = rsqrtf(ssh * (1.f / 2048.f) + 1e-6f);
  const float rsk = rsqrtf(ssk * (1.f / 2048.f) + 1e-6f);
  const float dot = rsh * rsk * shk;
  const float rg = 1.f / (1.f + __expf(-dot * 0.02209708691207961f));
  const float gate = fmaxf(rg, 0.5f);
  if (tid == 0) gate_out[t] = gate;
#pragma unroll
  for (int i = 0; i < 8; ++i) {
    int cc = tid + i * 256;
    gatedb[(size_t)t * CDIM + cc] = f2bf(gate * vv[i]);
  }
}

// ---------------- causal depthwise conv (K=3) + silu ----------------
__global__ __launch_bounds__(256) void conv_kernel(
    const unsigned short* __restrict__ gatedb, const float* __restrict__ convw,
    float* __restrict__ out0) {
  const int t = blockIdx.x, tid = threadIdx.x;
  const int l = t & 1023;
  const int c0 = tid * 8;
  bf16x8 gz;
#pragma unroll
  for (int j = 0; j < 8; ++j) gz[j] = 0;
  bf16x8 g2 = *reinterpret_cast<const bf16x8*>(gatedb + (size_t)t * CDIM + c0);
  bf16x8 g1 = (l >= 1) ? *reinterpret_cast<const bf16x8*>(gatedb + (size_t)(t - 1) * CDIM + c0) : gz;
  bf16x8 g0 = (l >= 2) ? *reinterpret_cast<const bf16x8*>(gatedb + (size_t)(t - 2) * CDIM + c0) : gz;
  float res[8];
#pragma unroll
  for (int j = 0; j < 8; ++j) {
    int c = c0 + j;
    float x = convw[c * 3 + 0] * bf2f((unsigned short)g0[j])
            + convw[c * 3 + 1] * bf2f((unsigned short)g1[j])
            + convw[c * 3 + 2] * bf2f((unsigned short)g2[j]);
    res[j] = x / (1.f + __expf(-x));
  }
  *reinterpret_cast<float4*>(out0 + (size_t)t * CDIM + c0) =
      make_float4(res[0], res[1], res[2], res[3]);
  *reinterpret_cast<float4*>(out0 + (size_t)t * CDIM + c0 + 4) =
      make_float4(res[4], res[5], res[6], res[7]);
}

extern "C" void kernel_launch(void* const* d_in, const int* in_sizes, int n_in,
                              void* d_out, int out_size, void* d_ws, size_t ws_size,
                              hipStream_t stream) {
  const float* hidden = (const float*)d_in[0];
  const float* table  = (const float*)d_in[1];
  const float* Wq     = (const float*)d_in[2];
  const float* ln_g   = (const float*)d_in[3];
  const float* ln_b   = (const float*)d_in[4];
  const float* Wk     = (const float*)d_in[5];
  const float* Wv     = (const float*)d_in[6];
  const float* gnw    = (const float*)d_in[7];
  const float* knw    = (const float*)d_in[8];
  const float* convw  = (const float*)d_in[9];
  float* out = (float*)d_out;

  char* w = (char*)d_ws;
  const size_t MB = 1u << 20;
  // time-sliced layout (70 MB total):
  unsigned short* hb     = (unsigned short*)(w);            // 16MB  [A->B]
  unsigned short* qb     = (unsigned short*)(w + 16 * MB);  // 2MB   [B]
  unsigned short* Opart  = (unsigned short*)(w);            // 32MB  [C->D]
  unsigned short* gatedb = (unsigned short*)(w);            // 16MB  [F->G]
  unsigned short* qn     = (unsigned short*)(w + 32 * MB);  // 2MB   [B->C]
  unsigned short* retr   = (unsigned short*)(w + 32 * MB);  // 2MB   [D->E]
  unsigned short* WkvT   = (unsigned short*)(w + 34 * MB);  // 2MB   [A->E]
  unsigned short* WqT    = (unsigned short*)(w + 36 * MB);  // 1MB   [A->B]
  float*          lpart  = (float*)(w + 37 * MB);           // 256KB [C->D]
  unsigned short* tnb    = (unsigned short*)(w + 38 * MB);  // 16MB  [A->C]
  unsigned short* tvb    = (unsigned short*)(w + 54 * MB);  // 16MB  [A->C]
  unsigned short* kv     = (unsigned short*)(w + 38 * MB);  // 32MB  [E->F]

  cast_bf16_kernel<<<NTOK * CDIM / 2048, 256, 0, stream>>>(hidden, hb);
  transpose_cast_kernel<<<dim3(64, 8), 256, 0, stream>>>(Wq, WqT, CDIM, EDIM);
  transpose_cast_kernel<<<dim3(8, 64), 256, 0, stream>>>(Wk, WkvT, EDIM, CDIM);
  transpose_cast_kernel<<<dim3(8, 64), 256, 0, stream>>>(Wv, WkvT + (size_t)CDIM * EDIM, EDIM, CDIM);
  tabprep_kernel<<<TROWS / 32, 256, 0, stream>>>(table, tnb, tvb);
  gemm_bt_kernel<<<(NTOK / 128) * (EDIM / 128), 256, 0, stream>>>(hb, WqT, qb, NTOK, EDIM, CDIM);
  normq_kernel<<<NTOK, 64, 0, stream>>>(qb, qn);
  attn_kernel<<<dim3(NTOK / 128, SPLIT), 256, 0, stream>>>(qn, tnb, tvb, Opart, lpart);
  combine_ln_kernel<<<NTOK, 256, 0, stream>>>(Opart, lpart, ln_g, ln_b, retr);
  gemm_bt_kernel<<<(NTOK / 128) * (2 * CDIM / 128), 256, 0, stream>>>(retr, WkvT, kv, NTOK, 2 * CDIM, EDIM);
  gate_kernel<<<NTOK, 256, 0, stream>>>(hidden, kv, gnw, knw, gatedb, out + OUT0);
  conv_kernel<<<NTOK, 256, 0, stream>>>(gatedb, convw, out);
}

// Round 3
// 230.021 us; speedup vs baseline: 2.8328x; 1.0682x over previous
//
#include <hip/hip_runtime.h>
#include <stdint.h>

// EngramANNInjection v3: 8-wave/256-token attention block (PV e-split across
// waves, block-shared P buffer), fixed softmax max (=16), split-K qproj with
// fused l2norm combine, bf16 MFMA GEMMs.

#define NTOK 4096
#define CDIM 2048
#define EDIM 256
#define TROWS 32768
#define SPLIT 16
#define OUT0 (NTOK * CDIM)

typedef __attribute__((ext_vector_type(8))) short bf16x8;
typedef __attribute__((ext_vector_type(4))) float f32x4;

__device__ inline float bf2f(unsigned short u) { return __uint_as_float((unsigned)u << 16); }
__device__ inline unsigned short f2bf(float f) {
  unsigned x = __float_as_uint(f);
  x += 0x7fffu + ((x >> 16) & 1u);  // RNE
  return (unsigned short)(x >> 16);
}
__device__ inline unsigned cvt_pk_bf16(float lo, float hi) {
  unsigned r;
  asm("v_cvt_pk_bf16_f32 %0, %1, %2" : "=v"(r) : "v"(lo), "v"(hi));
  return r;
}
__device__ inline void gll16(const void* g, void* l) {
  __builtin_amdgcn_global_load_lds((const __attribute__((address_space(1))) void*)g,
                                   (__attribute__((address_space(3))) void*)l, 16, 0, 0);
}

// ---------------- fp32 -> bf16 cast (hidden) ----------------
__global__ __launch_bounds__(256) void cast_bf16_kernel(
    const float* __restrict__ in, unsigned short* __restrict__ out) {
  const int idx = blockIdx.x * 256 + threadIdx.x;
  float4 v0 = *reinterpret_cast<const float4*>(&in[(size_t)idx * 8]);
  float4 v1 = *reinterpret_cast<const float4*>(&in[(size_t)idx * 8 + 4]);
  bf16x8 o;
  o[0] = (short)f2bf(v0.x); o[1] = (short)f2bf(v0.y);
  o[2] = (short)f2bf(v0.z); o[3] = (short)f2bf(v0.w);
  o[4] = (short)f2bf(v1.x); o[5] = (short)f2bf(v1.y);
  o[6] = (short)f2bf(v1.z); o[7] = (short)f2bf(v1.w);
  *reinterpret_cast<bf16x8*>(&out[(size_t)idx * 8]) = o;
}

// ---------------- transpose + cast: in f32 [R][C] -> out bf16 [C][R] ----------------
__global__ __launch_bounds__(256) void transpose_cast_kernel(
    const float* __restrict__ in0, const float* __restrict__ in1,
    unsigned short* __restrict__ out, int R, int C) {
  __shared__ float lt[32][33];
  const int tid = threadIdx.x;
  const int r0 = blockIdx.x * 32, c0 = blockIdx.y * 32;
  const float* in = blockIdx.z ? in1 : in0;
  unsigned short* op = out + (size_t)blockIdx.z * R * C;
  {
    int r = tid >> 3, c4 = (tid & 7) * 4;
    float4 v = *reinterpret_cast<const float4*>(&in[(size_t)(r0 + r) * C + c0 + c4]);
    lt[r][c4] = v.x; lt[r][c4 + 1] = v.y; lt[r][c4 + 2] = v.z; lt[r][c4 + 3] = v.w;
  }
  __syncthreads();
  {
    int c = tid >> 3, r4 = (tid & 7) * 4;
#pragma unroll
    for (int j = 0; j < 4; ++j)
      op[(size_t)(c0 + c) * R + r0 + r4 + j] = f2bf(lt[r4 + j][c]);
  }
}

// ---------------- table prep: normalized K (blocked) + raw V (blocked) ----------------
__global__ __launch_bounds__(256) void tabprep_kernel(
    const float* __restrict__ table, unsigned short* __restrict__ tnb,
    unsigned short* __restrict__ tvb) {
  __shared__ float lt[32][257];
  __shared__ float inv[32];
  const int tid = threadIdx.x, nb = blockIdx.x;
  const int r0 = nb * 32;
#pragma unroll
  for (int i = 0; i < 8; ++i) {
    int id = i * 256 + tid;
    int row = id >> 6, e4 = (id & 63) * 4;
    float4 v = *reinterpret_cast<const float4*>(&table[(size_t)(r0 + row) * EDIM + e4]);
    lt[row][e4] = v.x; lt[row][e4 + 1] = v.y; lt[row][e4 + 2] = v.z; lt[row][e4 + 3] = v.w;
  }
  __syncthreads();
  {
    int row = tid >> 3, sub = tid & 7;
    float ss = 0.f;
#pragma unroll
    for (int j = 0; j < 32; ++j) { float v = lt[row][sub + 8 * j]; ss = fmaf(v, v, ss); }
    ss += __shfl_xor(ss, 1); ss += __shfl_xor(ss, 2); ss += __shfl_xor(ss, 4);
    if (sub == 0) inv[row] = 1.f / fmaxf(sqrtf(ss), 1e-8f);
  }
  __syncthreads();
#pragma unroll
  for (int i = 0; i < 4; ++i) {
    int q = i * 256 + tid;
    {
      int c8 = q >> 5, row = q & 31;
      bf16x8 v;
#pragma unroll
      for (int j = 0; j < 8; ++j) v[j] = (short)f2bf(lt[row][c8 * 8 + j] * inv[row]);
      *reinterpret_cast<bf16x8*>(&tnb[(size_t)nb * 8192 + q * 8]) = v;
    }
    {
      int hi = q >> 8, e = q & 255;
      bf16x8 v;
#pragma unroll
      for (int j = 0; j < 8; ++j) v[j] = (short)f2bf(lt[hi * 8 + j][e]);
      *reinterpret_cast<bf16x8*>(&tvb[(size_t)nb * 8192 + q * 8]) = v;
    }
  }
}

// ---------------- generic bf16 GEMM: C = A[M][Kfull](koff..) * BT[N][Kfull]^T ----------------
template <bool F32OUT>
__global__ __launch_bounds__(256, 2) void gemm_bt_kernel(
    const unsigned short* __restrict__ A, const unsigned short* __restrict__ BT,
    void* __restrict__ Cout, int M, int N, int Kfull, int klen) {
  __shared__ alignas(16) unsigned short sA[2][128 * 64];
  __shared__ alignas(16) unsigned short sB[2][128 * 64];
  const int tid = threadIdx.x;
  const int lane = tid & 63;
  const int wave = tid >> 6;
  const int laneLo = lane & 15, laneHi = lane >> 4;
  const int nbn = N >> 7;
  const int bm = blockIdx.x / nbn, bn = blockIdx.x % nbn;
  const int koff = blockIdx.y * klen;
  const int wr = wave >> 1, wc = wave & 1;
  f32x4 acc[4][4];
#pragma unroll
  for (int m = 0; m < 4; ++m)
#pragma unroll
    for (int n = 0; n < 4; ++n) acc[m][n] = (f32x4){0.f, 0.f, 0.f, 0.f};
  const int nkt = klen >> 6;
  auto STAGE = [&](int b, int kt) {
#pragma unroll
    for (int i = 0; i < 4; ++i) {
      int q = i * 256 + tid;
      int row = q >> 3, cl = q & 7;
      int cs = cl ^ (row & 7);
      gll16(A + ((size_t)(bm * 128 + row) * Kfull + koff + kt * 64 + cs * 8), &sA[b][q * 8]);
      gll16(BT + ((size_t)(bn * 128 + row) * Kfull + koff + kt * 64 + cs * 8), &sB[b][q * 8]);
    }
  };
  STAGE(0, 0);
  for (int kt = 0; kt < nkt; ++kt) {
    __syncthreads();
    if (kt + 1 < nkt) STAGE((kt & 1) ^ 1, kt + 1);
    const unsigned short* pA = sA[kt & 1];
    const unsigned short* pB = sB[kt & 1];
#pragma unroll
    for (int ks = 0; ks < 2; ++ks) {
      bf16x8 af[4], bfr[4];
#pragma unroll
      for (int m = 0; m < 4; ++m) {
        int row = wr * 64 + m * 16 + laneLo;
        af[m] = *reinterpret_cast<const bf16x8*>(&pA[(row * 8 + ((ks * 4 + laneHi) ^ (row & 7))) * 8]);
      }
#pragma unroll
      for (int n = 0; n < 4; ++n) {
        int row = wc * 64 + n * 16 + laneLo;
        bfr[n] = *reinterpret_cast<const bf16x8*>(&pB[(row * 8 + ((ks * 4 + laneHi) ^ (row & 7))) * 8]);
      }
#pragma unroll
      for (int m = 0; m < 4; ++m)
#pragma unroll
        for (int n = 0; n < 4; ++n)
          acc[m][n] = __builtin_amdgcn_mfma_f32_16x16x32_bf16(af[m], bfr[n], acc[m][n], 0, 0, 0);
    }
  }
#pragma unroll
  for (int m = 0; m < 4; ++m)
#pragma unroll
    for (int n = 0; n < 4; ++n)
#pragma unroll
      for (int r = 0; r < 4; ++r) {
        size_t idx = (size_t)(bm * 128 + wr * 64 + m * 16 + laneHi * 4 + r) * N +
                     bn * 128 + wc * 64 + n * 16 + laneLo;
        if (F32OUT)
          ((float*)Cout)[(size_t)blockIdx.y * M * N + idx] = acc[m][n][r];
        else
          ((unsigned short*)Cout)[idx] = f2bf(acc[m][n][r]);
      }
}

// ---------------- combine split-K partials + l2-norm -> qn bf16 ----------------
__global__ __launch_bounds__(256) void qcombine_kernel(
    const float* __restrict__ qpart, unsigned short* __restrict__ qn) {
  __shared__ float red[4];
  const int t = blockIdx.x, e = threadIdx.x;
  const int wave = e >> 6, lane = e & 63;
  float v = qpart[(size_t)t * EDIM + e] + qpart[((size_t)NTOK + t) * EDIM + e];
  float ss = v * v;
#pragma unroll
  for (int m = 1; m <= 32; m <<= 1) ss += __shfl_xor(ss, m);
  if (lane == 0) red[wave] = ss;
  __syncthreads();
  ss = red[0] + red[1] + red[2] + red[3];
  const float inv = 1.f / fmaxf(sqrtf(ss), 1e-8f);
  qn[(size_t)t * EDIM + e] = f2bf(v * inv);
}

// ---------------- flash attention: 8 waves, 256 tokens/block, PV e-split ----------------
__global__ __launch_bounds__(512, 2) void attn_kernel(
    const unsigned short* __restrict__ qn, const unsigned short* __restrict__ tnb,
    const unsigned short* __restrict__ tvb, unsigned short* __restrict__ Opart,
    float* __restrict__ lpart) {
  __shared__ alignas(16) unsigned short bufK[2][8192];
  __shared__ alignas(16) unsigned short bufV[2][8192];
  __shared__ alignas(16) unsigned short pbuf[16][16][40];  // [group][token][n], 80B rows
  const int tid = threadIdx.x;
  const int wave = tid >> 6, lane = tid & 63;
  const int Lo = lane & 15, Hi = lane >> 4;
  // XCD-chunked swizzle: 2 splits (4MB of table) per XCD
  const int cid = (blockIdx.x & 7) * 32 + (blockIdx.x >> 3);
  const int split = cid >> 4, tb = cid & 15;
  const int qkBase = tb * 256 + wave * 32;          // QK: 32 tokens per wave
  bf16x8 qf[2][8];
#pragma unroll
  for (int g = 0; g < 2; ++g)
#pragma unroll
    for (int ks = 0; ks < 8; ++ks)
      qf[g][ks] = *reinterpret_cast<const bf16x8*>(
          qn + (size_t)(qkBase + g * 16 + Lo) * EDIM + ks * 32 + Hi * 8);
  const int pvG = (wave & 3) * 4;                   // PV: 64 tokens x 128 e per wave
  const int pvF = (wave >> 2) * 8;
  f32x4 o[4][8];
#pragma unroll
  for (int ng = 0; ng < 4; ++ng)
#pragma unroll
    for (int f = 0; f < 8; ++f) o[ng][f] = (f32x4){0.f, 0.f, 0.f, 0.f};
  float l_run[2] = {0.f, 0.f};
  const int nt = (TROWS / SPLIT) / 32;  // 64
  const int nb0 = split * nt;
#pragma unroll
  for (int i = 0; i < 2; ++i) {
    gll16(tnb + (size_t)nb0 * 8192 + (i * 512 + tid) * 8, &bufK[0][(i * 512 + tid) * 8]);
    gll16(tvb + (size_t)nb0 * 8192 + (i * 512 + tid) * 8, &bufV[0][(i * 512 + tid) * 8]);
  }
  for (int it = 0; it < nt; ++it) {
    const int cur = it & 1;
    __syncthreads();  // staging of buf[cur] complete; pbuf free
    // ---- QK^T: S^T[n][tok] ----
    f32x4 z00 = {0.f, 0.f, 0.f, 0.f}, z01 = z00, z10 = z00, z11 = z00;
    __builtin_amdgcn_s_setprio(1);
#pragma unroll
    for (int ks = 0; ks < 8; ++ks) {
      bf16x8 a0 = *reinterpret_cast<const bf16x8*>(&bufK[cur][((ks * 4 + Hi) * 32 + Lo) * 8]);
      bf16x8 a1 = *reinterpret_cast<const bf16x8*>(&bufK[cur][((ks * 4 + Hi) * 32 + 16 + Lo) * 8]);
      z00 = __builtin_amdgcn_mfma_f32_16x16x32_bf16(a0, qf[0][ks], z00, 0, 0, 0);
      z01 = __builtin_amdgcn_mfma_f32_16x16x32_bf16(a1, qf[0][ks], z01, 0, 0, 0);
      z10 = __builtin_amdgcn_mfma_f32_16x16x32_bf16(a0, qf[1][ks], z10, 0, 0, 0);
      z11 = __builtin_amdgcn_mfma_f32_16x16x32_bf16(a1, qf[1][ks], z11, 0, 0, 0);
    }
    __builtin_amdgcn_s_setprio(0);
    // ---- softmax, fixed max 16: p = exp(16z - 16) ----
#pragma unroll
    for (int g = 0; g < 2; ++g) {
      const f32x4 za = g ? z10 : z00;
      const f32x4 zb = g ? z11 : z01;
      float p[8];
#pragma unroll
      for (int r = 0; r < 4; ++r) {
        p[r] = __expf(fmaf(16.f, za[r], -16.f));
        p[4 + r] = __expf(fmaf(16.f, zb[r], -16.f));
      }
      l_run[g] += ((p[0] + p[1]) + (p[2] + p[3])) + ((p[4] + p[5]) + (p[6] + p[7]));
      unsigned short* pb = &pbuf[wave * 2 + g][Lo][0];
      *reinterpret_cast<uint2*>(pb + Hi * 4) =
          make_uint2(cvt_pk_bf16(p[0], p[1]), cvt_pk_bf16(p[2], p[3]));
      *reinterpret_cast<uint2*>(pb + 16 + Hi * 4) =
          make_uint2(cvt_pk_bf16(p[4], p[5]), cvt_pk_bf16(p[6], p[7]));
    }
    __syncthreads();  // pbuf visible to all waves (vmcnt already 0 here)
    if (it + 1 < nt) {
#pragma unroll
      for (int i = 0; i < 2; ++i) {
        gll16(tnb + (size_t)(nb0 + it + 1) * 8192 + (i * 512 + tid) * 8,
              &bufK[cur ^ 1][(i * 512 + tid) * 8]);
        gll16(tvb + (size_t)(nb0 + it + 1) * 8192 + (i * 512 + tid) * 8,
              &bufV[cur ^ 1][(i * 512 + tid) * 8]);
      }
    }
    // ---- PV: 64 tokens x 128 e per wave ----
    bf16x8 pa0 = *reinterpret_cast<const bf16x8*>(&pbuf[pvG + 0][Lo][Hi * 8]);
    bf16x8 pa1 = *reinterpret_cast<const bf16x8*>(&pbuf[pvG + 1][Lo][Hi * 8]);
    bf16x8 pa2 = *reinterpret_cast<const bf16x8*>(&pbuf[pvG + 2][Lo][Hi * 8]);
    bf16x8 pa3 = *reinterpret_cast<const bf16x8*>(&pbuf[pvG + 3][Lo][Hi * 8]);
    __builtin_amdgcn_s_setprio(1);
#pragma unroll
    for (int f = 0; f < 8; ++f) {
      bf16x8 vb = *reinterpret_cast<const bf16x8*>(
          &bufV[cur][(Hi * 256 + (pvF + f) * 16 + Lo) * 8]);
      o[0][f] = __builtin_amdgcn_mfma_f32_16x16x32_bf16(pa0, vb, o[0][f], 0, 0, 0);
      o[1][f] = __builtin_amdgcn_mfma_f32_16x16x32_bf16(pa1, vb, o[1][f], 0, 0, 0);
      o[2][f] = __builtin_amdgcn_mfma_f32_16x16x32_bf16(pa2, vb, o[2][f], 0, 0, 0);
      o[3][f] = __builtin_amdgcn_mfma_f32_16x16x32_bf16(pa3, vb, o[3][f], 0, 0, 0);
    }
    __builtin_amdgcn_s_setprio(0);
  }
  // ---- epilogue ----
#pragma unroll
  for (int g = 0; g < 2; ++g) {
    float l = l_run[g];
    l += __shfl_xor(l, 16);
    l += __shfl_xor(l, 32);
    if (lane < 16) lpart[(size_t)split * NTOK + qkBase + g * 16 + Lo] = l;
  }
#pragma unroll
  for (int ng = 0; ng < 4; ++ng)
#pragma unroll
    for (int f = 0; f < 8; ++f)
#pragma unroll
      for (int r = 0; r < 4; ++r) {
        int token = tb * 256 + (pvG + ng) * 16 + Hi * 4 + r;
        Opart[((size_t)split * NTOK + token) * EDIM + (pvF + f) * 16 + Lo] =
            f2bf(o[ng][f][r]);
      }
}

// ---------------- combine splits (plain sum) + layernorm ----------------
__global__ __launch_bounds__(256) void combine_ln_kernel(
    const unsigned short* __restrict__ Opart, const float* __restrict__ lpart,
    const float* __restrict__ gamma, const float* __restrict__ beta,
    unsigned short* __restrict__ retr) {
  __shared__ float red[4][2];
  const int t = blockIdx.x, e = threadIdx.x;
  const int wave = e >> 6, lane = e & 63;
  float acc = 0.f, l = 0.f;
#pragma unroll
  for (int s = 0; s < SPLIT; ++s) {
    acc += bf2f(Opart[((size_t)s * NTOK + t) * EDIM + e]);
    l += lpart[(size_t)s * NTOK + t];
  }
  const float r = acc / l;
  float s1 = r, s2 = r * r;
#pragma unroll
  for (int m = 1; m <= 32; m <<= 1) { s1 += __shfl_xor(s1, m); s2 += __shfl_xor(s2, m); }
  if (lane == 0) { red[wave][0] = s1; red[wave][1] = s2; }
  __syncthreads();
  s1 = red[0][0] + red[1][0] + red[2][0] + red[3][0];
  s2 = red[0][1] + red[1][1] + red[2][1] + red[3][1];
  const float mu = s1 * (1.f / 256.f);
  const float var = s2 * (1.f / 256.f) - mu * mu;
  const float rs = rsqrtf(var + 1e-6f);
  retr[(size_t)t * EDIM + e] = f2bf((r - mu) * rs * gamma[e] + beta[e]);
}

// ---------------- rmsnorms + gate + gated ----------------
__global__ __launch_bounds__(256) void gate_kernel(
    const float* __restrict__ hidden, const unsigned short* __restrict__ kv,
    const float* __restrict__ gw, const float* __restrict__ kwn,
    unsigned short* __restrict__ gatedb, float* __restrict__ gate_out) {
  __shared__ float red[4][3];
  const int t = blockIdx.x, tid = threadIdx.x;
  const int wave = tid >> 6, lane = tid & 63;
  float vv[8];
  float ssh = 0.f, ssk = 0.f, shk = 0.f;
#pragma unroll
  for (int i = 0; i < 8; ++i) {
    int cc = tid + i * 256;
    float h = hidden[(size_t)t * CDIM + cc];
    float k = bf2f(kv[(size_t)t * 4096 + cc]);
    vv[i] = bf2f(kv[(size_t)t * 4096 + 2048 + cc]);
    ssh = fmaf(h, h, ssh);
    ssk = fmaf(k, k, ssk);
    shk = fmaf(h * gw[cc], k * kwn[cc], shk);
  }
#pragma unroll
  for (int m = 1; m <= 32; m <<= 1) {
    ssh += __shfl_xor(ssh, m); ssk += __shfl_xor(ssk, m); shk += __shfl_xor(shk, m);
  }
  if (lane == 0) { red[wave][0] = ssh; red[wave][1] = ssk; red[wave][2] = shk; }
  __syncthreads();
  ssh = red[0][0] + red[1][0] + red[2][0] + red[3][0];
  ssk = red[0][1] + red[1][1] + red[2][1] + red[3][1];
  shk = red[0][2] + red[1][2] + red[2][2] + red[3][2];
  const float rsh = rsqrtf(ssh * (1.f / 2048.f) + 1e-6f);
  const float rsk = rsqrtf(ssk * (1.f / 2048.f) + 1e-6f);
  const float dot = rsh * rsk * shk;
  const float rg = 1.f / (1.f + __expf(-dot * 0.02209708691207961f));
  const float gate = fmaxf(rg, 0.5f);
  if (tid == 0) gate_out[t] = gate;
#pragma unroll
  for (int i = 0; i < 8; ++i) {
    int cc = tid + i * 256;
    gatedb[(size_t)t * CDIM + cc] = f2bf(gate * vv[i]);
  }
}

// ---------------- causal depthwise conv (K=3) + silu ----------------
__global__ __launch_bounds__(256) void conv_kernel(
    const unsigned short* __restrict__ gatedb, const float* __restrict__ convw,
    float* __restrict__ out0) {
  const int t = blockIdx.x, tid = threadIdx.x;
  const int l = t & 1023;
  const int c0 = tid * 8;
  bf16x8 gz;
#pragma unroll
  for (int j = 0; j < 8; ++j) gz[j] = 0;
  bf16x8 g2 = *reinterpret_cast<const bf16x8*>(gatedb + (size_t)t * CDIM + c0);
  bf16x8 g1 = (l >= 1) ? *reinterpret_cast<const bf16x8*>(gatedb + (size_t)(t - 1) * CDIM + c0) : gz;
  bf16x8 g0 = (l >= 2) ? *reinterpret_cast<const bf16x8*>(gatedb + (size_t)(t - 2) * CDIM + c0) : gz;
  float res[8];
#pragma unroll
  for (int j = 0; j < 8; ++j) {
    int c = c0 + j;
    float x = convw[c * 3 + 0] * bf2f((unsigned short)g0[j])
            + convw[c * 3 + 1] * bf2f((unsigned short)g1[j])
            + convw[c * 3 + 2] * bf2f((unsigned short)g2[j]);
    res[j] = x / (1.f + __expf(-x));
  }
  *reinterpret_cast<float4*>(out0 + (size_t)t * CDIM + c0) =
      make_float4(res[0], res[1], res[2], res[3]);
  *reinterpret_cast<float4*>(out0 + (size_t)t * CDIM + c0 + 4) =
      make_float4(res[4], res[5], res[6], res[7]);
}

extern "C" void kernel_launch(void* const* d_in, const int* in_sizes, int n_in,
                              void* d_out, int out_size, void* d_ws, size_t ws_size,
                              hipStream_t stream) {
  const float* hidden = (const float*)d_in[0];
  const float* table  = (const float*)d_in[1];
  const float* Wq     = (const float*)d_in[2];
  const float* ln_g   = (const float*)d_in[3];
  const float* ln_b   = (const float*)d_in[4];
  const float* Wk     = (const float*)d_in[5];
  const float* Wv     = (const float*)d_in[6];
  const float* gnw    = (const float*)d_in[7];
  const float* knw    = (const float*)d_in[8];
  const float* convw  = (const float*)d_in[9];
  float* out = (float*)d_out;

  char* w = (char*)d_ws;
  const size_t MB = 1u << 20;
  // peak 69 MB:
  unsigned short* tnb    = (unsigned short*)(w);            // 16MB [A->C]
  unsigned short* tvb    = (unsigned short*)(w + 16 * MB);  // 16MB [A->C]
  unsigned short* kv     = (unsigned short*)(w);            // 32MB [E->F] (over tnb+tvb)
  unsigned short* qn     = (unsigned short*)(w + 32 * MB);  // 2MB  [B->C]
  unsigned short* retr   = (unsigned short*)(w + 32 * MB);  // 2MB  [D->E] (over qn)
  unsigned short* WkvT   = (unsigned short*)(w + 34 * MB);  // 2MB  [A->E]
  float*          lpart  = (float*)(w + 36 * MB);           // 256KB [C->D]
  unsigned short* Opart  = (unsigned short*)(w + 37 * MB);  // 32MB [C->D]
  unsigned short* hb     = (unsigned short*)(w + 37 * MB);  // 16MB [A->B] (over Opart)
  unsigned short* WqT    = (unsigned short*)(w + 53 * MB);  // 1MB  [A->B]
  float*          qpart  = (float*)(w + 54 * MB);           // 8MB  [B]
  unsigned short* gatedb = (unsigned short*)(w + 37 * MB);  // 16MB [F->G] (over Opart)

  cast_bf16_kernel<<<NTOK * CDIM / 2048, 256, 0, stream>>>(hidden, hb);
  transpose_cast_kernel<<<dim3(64, 8, 1), 256, 0, stream>>>(Wq, Wq, WqT, CDIM, EDIM);
  transpose_cast_kernel<<<dim3(8, 64, 2), 256, 0, stream>>>(Wk, Wv, WkvT, EDIM, CDIM);
  tabprep_kernel<<<TROWS / 32, 256, 0, stream>>>(table, tnb, tvb);
  gemm_bt_kernel<true><<<dim3((NTOK / 128) * (EDIM / 128), 2), 256, 0, stream>>>(
      hb, WqT, qpart, NTOK, EDIM, CDIM, 1024);
  qcombine_kernel<<<NTOK, 256, 0, stream>>>(qpart, qn);
  attn_kernel<<<16 * SPLIT, 512, 0, stream>>>(qn, tnb, tvb, Opart, lpart);
  combine_ln_kernel<<<NTOK, 256, 0, stream>>>(Opart, lpart, ln_g, ln_b, retr);
  gemm_bt_kernel<false><<<dim3((NTOK / 128) * (2 * CDIM / 128), 1), 256, 0, stream>>>(
      retr, WkvT, kv, NTOK, 2 * CDIM, EDIM, EDIM);
  gate_kernel<<<NTOK, 256, 0, stream>>>(hidden, kv, gnw, knw, gatedb, out + OUT0);
  conv_kernel<<<NTOK, 256, 0, stream>>>(gatedb, convw, out);
}